// Round 7
// baseline (417.381 us; speedup 1.0000x reference)
//
#include <hip/hip_runtime.h>

#define Kst 256
#define Dd 256
#define Vv 50000
#define Tt 512
#define Bb 256
#define KP1 257
#define MD 512
#define NROWS (KP1*KP1)   // 66049
#define EPSf 1e-5f

#define VB2 196           // ceil(50000/256) vocab blocks for MFMA emission kernel

typedef __attribute__((ext_vector_type(8))) short short8;
typedef __attribute__((ext_vector_type(4))) short short4v;
typedef __attribute__((ext_vector_type(4))) float f32x4;
typedef __attribute__((ext_vector_type(4))) unsigned u32x4;
typedef __attribute__((ext_vector_type(2))) unsigned u32x2;

__device__ __forceinline__ unsigned short f2bf(float f) {
    unsigned u = __builtin_bit_cast(unsigned, f);
    unsigned r = (u + 0x7fffu + ((u >> 16) & 1u)) >> 16;
    return (unsigned short)r;
}
__device__ __forceinline__ float bf2f(unsigned short u) {
    return __builtin_bit_cast(float, ((unsigned)u) << 16);
}
__device__ __forceinline__ unsigned bfpack(float lo, float hi) {
    return __builtin_amdgcn_perm(__builtin_bit_cast(unsigned, hi),
                                 __builtin_bit_cast(unsigned, lo), 0x07060302u);
}

// ---------------- K1: emission hidden h = LN(lembs + relu(lembs@em_W.T + b)) -> bf16 ----------------
__global__ __launch_bounds__(256) void k_h(
    const float* __restrict__ lembs, const float* __restrict__ em_W,
    const float* __restrict__ em_bias, const float* __restrict__ em_g,
    const float* __restrict__ em_beta, unsigned short* __restrict__ h_bf)
{
    int k = blockIdx.x, d = threadIdx.x;
    __shared__ float lrow[Dd];
    __shared__ float red[256];
    lrow[d] = lembs[k*Dd + d];
    __syncthreads();
    float acc = em_bias[d];
    const float4* w4 = (const float4*)(em_W + (size_t)d*Dd);
    for (int j4 = 0; j4 < Dd/4; ++j4) {
        float4 w = w4[j4];
        acc += w.x*lrow[4*j4] + w.y*lrow[4*j4+1] + w.z*lrow[4*j4+2] + w.w*lrow[4*j4+3];
    }
    float val = lrow[d] + fmaxf(acc, 0.f);
    red[d] = val; __syncthreads();
    for (int s = 128; s > 0; s >>= 1) { if (d < s) red[d] += red[d+s]; __syncthreads(); }
    float mu = red[0] * (1.f/Dd);
    __syncthreads();
    float c = val - mu;
    red[d] = c*c; __syncthreads();
    for (int s = 128; s > 0; s >>= 1) { if (d < s) red[d] += red[d+s]; __syncthreads(); }
    float rstd = rsqrtf(red[0] * (1.f/Dd) + EPSf);
    float o = c * rstd * em_g[d] + em_beta[d];
    h_bf[k*Dd + d] = f2bf(o);
}

// ---------------- K2: P0[i,j] = tlembs[i]@tm_W[j,0:256], P1[i,j] = tlembs[i]@tm_W[j,256:512] ----------------
__global__ __launch_bounds__(256) void k_P(
    const float* __restrict__ tlembs, const float* __restrict__ tm_W,
    float* __restrict__ P0, float* __restrict__ P1)
{
    int i = blockIdx.x;            // 0..256
    int tid = threadIdx.x;
    __shared__ float tl[Dd];
    tl[tid] = tlembs[i*Dd + tid];
    __syncthreads();
    for (int half = 0; half < 2; ++half) {
        int j = tid + half*256;
        float a0 = 0.f, a1 = 0.f;
        const float4* w4 = (const float4*)(tm_W + (size_t)j*MD);
        for (int l4 = 0; l4 < 64; ++l4) {
            float4 w = w4[l4];
            a0 += w.x*tl[4*l4] + w.y*tl[4*l4+1] + w.z*tl[4*l4+2] + w.w*tl[4*l4+3];
        }
        for (int l4 = 64; l4 < 128; ++l4) {
            float4 w = w4[l4];
            int l = 4*l4 - 256;
            a1 += w.x*tl[l] + w.y*tl[l+1] + w.z*tl[l+2] + w.w*tl[l+3];
        }
        P0[(size_t)i*MD + j] = a0;
        P1[(size_t)i*MD + j] = a1;
    }
}

// ---------------- K2b: td_W -> bf16 copy ----------------
__global__ __launch_bounds__(256) void k_tdw(
    const float* __restrict__ td_W, unsigned short* __restrict__ tdw_bf)
{
    int i = blockIdx.x*256 + threadIdx.x;
    float4 v = ((const float4*)td_W)[i];
    short4v o;
    o.x = (short)f2bf(v.x); o.y = (short)f2bf(v.y);
    o.z = (short)f2bf(v.z); o.w = (short)f2bf(v.w);
    *(short4v*)(tdw_bf + (size_t)i*4) = o;
}

// ---------------- K2c: dec_W -> bf16 copy (50000*256 elems = 3.2M float4) ----------------
__global__ __launch_bounds__(256) void k_decw(
    const float* __restrict__ dec_W, unsigned short* __restrict__ decw_bf)
{
    int i = blockIdx.x*256 + threadIdx.x;    // grid 12500
    float4 v = ((const float4*)dec_W)[i];
    short4v o;
    o.x = (short)f2bf(v.x); o.y = (short)f2bf(v.y);
    o.z = (short)f2bf(v.z); o.w = (short)f2bf(v.w);
    *(short4v*)(decw_bf + (size_t)i*4) = o;
}

// ---------------- K3 (MFMA): emission logits E[v][k] (bf16) + logsumexp partials ----------------
// Block = 4 waves. M = 256 vocab rows (64/wave), N = 128 k-states (kg in {0,1}).
// A: decw_bf 16B loads (no repack). B: h_bf rows from LDS. E stored coalesced via LDS overlay.
__global__ __launch_bounds__(256) void k_em_mfma2(
    const unsigned short* __restrict__ decw_bf, const float* __restrict__ dec_b,
    const unsigned short* __restrict__ h_bf, float* __restrict__ part,
    unsigned short* __restrict__ E)
{
    int vb = blockIdx.x, kg = blockIdx.y;
    int tid = threadIdx.x, lane = tid & 63, wv = tid >> 6;
    int l15 = lane & 15, q = lane >> 4;
    __shared__ short hs[128][264];      // 67584 B; reused as st[256][132] for E staging
    __shared__ float red[4][128];
    __shared__ float gmax[128];
    short* st = (short*)hs;

    // stage h_bf rows [kg*128, kg*128+128): thread -> (row, half of 128 shorts)
    {
        int row = tid >> 1, c0 = (tid & 1) * 128;
        const short8* src = (const short8*)(h_bf + (size_t)(kg*128 + row)*Dd + c0);
        #pragma unroll
        for (int u = 0; u < 16; ++u)
            *(short8*)&hs[row][c0 + u*8] = src[u];
    }
    __syncthreads();

    const unsigned short* aptr[4];
    #pragma unroll
    for (int mt = 0; mt < 4; ++mt) {
        int v = vb*256 + wv*64 + mt*16 + l15;
        if (v > Vv-1) v = Vv-1;
        aptr[mt] = decw_bf + (size_t)v*Dd + q*8;
    }
    f32x4 acc[4][8];
    #pragma unroll
    for (int mt = 0; mt < 4; ++mt)
        #pragma unroll
        for (int nt = 0; nt < 8; ++nt)
            acc[mt][nt] = (f32x4){0.f,0.f,0.f,0.f};

    for (int ks = 0; ks < 8; ++ks) {
        short8 a[4];
        #pragma unroll
        for (int mt = 0; mt < 4; ++mt)
            a[mt] = *(const short8*)(aptr[mt] + ks*32);
        short8 b[8];
        #pragma unroll
        for (int nt = 0; nt < 8; ++nt)
            b[nt] = *(const short8*)&hs[nt*16 + l15][ks*32 + q*8];
        #pragma unroll
        for (int mt = 0; mt < 4; ++mt)
            #pragma unroll
            for (int nt = 0; nt < 8; ++nt)
                acc[mt][nt] = __builtin_amdgcn_mfma_f32_16x16x32_bf16(a[mt], b[nt], acc[mt][nt], 0,0,0);
    }

    // bias + OOB mask (C layout: row = q*4+reg within 16-tile, col = nt*16+l15)
    #pragma unroll
    for (int mt = 0; mt < 4; ++mt) {
        int vbase = vb*256 + wv*64 + mt*16 + q*4;
        #pragma unroll
        for (int reg = 0; reg < 4; ++reg) {
            int v = vbase + reg;
            if (v < Vv) {
                float db = dec_b[v];
                #pragma unroll
                for (int nt = 0; nt < 8; ++nt) acc[mt][nt][reg] += db;
            } else {
                #pragma unroll
                for (int nt = 0; nt < 8; ++nt) acc[mt][nt][reg] = -1e30f;
            }
        }
    }
    // per-col max over wave's 64 rows
    float mx[8];
    #pragma unroll
    for (int nt = 0; nt < 8; ++nt) {
        float m = -1e30f;
        #pragma unroll
        for (int mt = 0; mt < 4; ++mt)
            #pragma unroll
            for (int reg = 0; reg < 4; ++reg)
                m = fmaxf(m, acc[mt][nt][reg]);
        m = fmaxf(m, __shfl_xor(m, 16));
        m = fmaxf(m, __shfl_xor(m, 32));
        mx[nt] = m;
    }
    if (q == 0)
        #pragma unroll
        for (int nt = 0; nt < 8; ++nt) red[wv][nt*16 + l15] = mx[nt];
    __syncthreads();                    // hs now reusable (all MFMA reads done)
    if (tid < 128)
        gmax[tid] = fmaxf(fmaxf(red[0][tid], red[1][tid]), fmaxf(red[2][tid], red[3][tid]));
    // stage logits bf16 into st overlay
    #pragma unroll
    for (int mt = 0; mt < 4; ++mt) {
        #pragma unroll
        for (int reg = 0; reg < 4; ++reg) {
            int rl = wv*64 + mt*16 + q*4 + reg;
            #pragma unroll
            for (int nt = 0; nt < 8; ++nt)
                st[rl*132 + nt*16 + l15] = (short)f2bf(acc[mt][nt][reg]);
        }
    }
    __syncthreads();                    // gmax ready + st staged + red free
    float sm[8];
    #pragma unroll
    for (int nt = 0; nt < 8; ++nt) {
        float g = gmax[nt*16 + l15];
        float s = 0.f;
        #pragma unroll
        for (int mt = 0; mt < 4; ++mt)
            #pragma unroll
            for (int reg = 0; reg < 4; ++reg)
                s += __expf(acc[mt][nt][reg] - g);
        s += __shfl_xor(s, 16);
        s += __shfl_xor(s, 32);
        sm[nt] = s;
    }
    if (q == 0)
        #pragma unroll
        for (int nt = 0; nt < 8; ++nt) red[wv][nt*16 + l15] = sm[nt];
    __syncthreads();
    if (tid < 128) {
        int kst = kg*128 + tid;
        float s = red[0][tid] + red[1][tid] + red[2][tid] + red[3][tid];
        part[((size_t)kst*VB2 + vb)*2]     = gmax[tid];
        part[((size_t)kst*VB2 + vb)*2 + 1] = s;
    }
    // coalesced E store: per wave-instr 4 rows x 256B; wave wv covers rows [wv*64, wv*64+64)
    {
        int rsub = lane >> 4;           // 0..3
        #pragma unroll
        for (int i = 0; i < 16; ++i) {
            int rl = wv*64 + i*4 + rsub;
            int vr = vb*256 + rl;
            if (vr < Vv)
                *(short8*)(E + (size_t)vr*Kst + kg*128 + l15*8) =
                    *(const short8*)&st[rl*132 + l15*8];
        }
    }
}

// ---------------- K4: combine partials -> lse_em[k] ----------------
__global__ __launch_bounds__(256) void k_em_comb(
    const float* __restrict__ part, float* __restrict__ lse_em)
{
    int k = threadIdx.x;
    float m = -1e30f, s = 0.f;
    for (int vb = 0; vb < VB2; ++vb) {
        float m2 = part[((size_t)k*VB2+vb)*2], s2 = part[((size_t)k*VB2+vb)*2+1];
        if (m2 > m) { s = s*__expf(m - m2) + s2; m = m2; }
        else          s += s2*__expf(m2 - m);
    }
    lse_em[k] = m + logf(s);
}

// ---------------- K5 (MFMA): transition logits Td[r][c] (bf16) + lse_t[r] ----------------
__global__ __launch_bounds__(256) void k_trans4(
    const float* __restrict__ tlembs, const float* __restrict__ P0,
    const float* __restrict__ P1, const float* __restrict__ tm_bias,
    const float* __restrict__ tn_g, const float* __restrict__ tn_beta,
    const short* __restrict__ tdw_bf, const float* __restrict__ td_b,
    float* __restrict__ lse_t, unsigned short* __restrict__ Td)
{
    __shared__ short th[64][520];          // 66.5 KB; row stride 1040B
    __shared__ float rstat[64][9];
    __shared__ float musig[64][2];
    __shared__ float pmax[4][64], psum[4][64], gmax[64];
    int tid = threadIdx.x, lane = tid & 63, wv = tid >> 6;
    int r0 = blockIdx.x * 64;

    // ---- phase A pass 1: coalesced, dependency-free staging ----
    {
        const float4* bias0 = (const float4*)tm_bias;
        const float4* bias1 = (const float4*)(tm_bias + 256);
        for (int i = 0; i < 16; ++i) {
            int row = wv*16 + i;
            int r = r0 + row; if (r >= NROWS) r = NROWS - 1;
            int i0 = r / KP1, i1 = r - i0*KP1;
            float4 a0 = ((const float4*)(P0 + (size_t)i0*MD))[lane];
            float4 b0 = ((const float4*)(P1 + (size_t)i1*MD))[lane];
            float4 t0 = ((const float4*)(tlembs + (size_t)i0*Dd))[lane];
            float4 c0 = bias0[lane];
            float4 a1 = ((const float4*)(P0 + (size_t)i0*MD + 256))[lane];
            float4 b1 = ((const float4*)(P1 + (size_t)i1*MD + 256))[lane];
            float4 t1 = ((const float4*)(tlembs + (size_t)i1*Dd))[lane];
            float4 c1 = bias1[lane];
            float v0 = t0.x + fmaxf(a0.x+b0.x+c0.x, 0.f);
            float v1 = t0.y + fmaxf(a0.y+b0.y+c0.y, 0.f);
            float v2 = t0.z + fmaxf(a0.z+b0.z+c0.z, 0.f);
            float v3 = t0.w + fmaxf(a0.w+b0.w+c0.w, 0.f);
            float v4 = t1.x + fmaxf(a1.x+b1.x+c1.x, 0.f);
            float v5 = t1.y + fmaxf(a1.y+b1.y+c1.y, 0.f);
            float v6 = t1.z + fmaxf(a1.z+b1.z+c1.z, 0.f);
            float v7 = t1.w + fmaxf(a1.w+b1.w+c1.w, 0.f);
            u32x2 p0; p0.x = bfpack(v0, v1); p0.y = bfpack(v2, v3);
            u32x2 p1; p1.x = bfpack(v4, v5); p1.y = bfpack(v6, v7);
            *(u32x2*)&th[row][lane*4]       = p0;
            *(u32x2*)&th[row][256 + lane*4] = p1;
        }
    }
    __syncthreads();
    // ---- pass 2: LN stats from LDS ----
    {
        int row = tid & 63, seg = tid >> 6;
        float s = 0.f, ss = 0.f;
        #pragma unroll
        for (int k8 = 0; k8 < 16; ++k8) {
            short8 vv = *(const short8*)&th[row][seg*128 + k8*8];
            #pragma unroll
            for (int e = 0; e < 8; ++e) {
                float f = bf2f((unsigned short)vv[e]);
                s += f; ss += f*f;
            }
        }
        rstat[row][seg]     = s;
        rstat[row][4 + seg] = ss;
    }
    __syncthreads();
    if (tid < 64) {
        float s  = (rstat[tid][0] + rstat[tid][1]) + (rstat[tid][2] + rstat[tid][3]);
        float ss = (rstat[tid][4] + rstat[tid][5]) + (rstat[tid][6] + rstat[tid][7]);
        float mu = s * (1.f/MD);
        musig[tid][0] = mu;
        musig[tid][1] = rsqrtf(ss*(1.f/MD) - mu*mu + EPSf);
    }
    __syncthreads();
    // ---- pass 3: normalize in place ----
    {
        int row = tid & 63, seg = tid >> 6;
        float mu = musig[row][0], rs = musig[row][1];
        const float4* g4 = (const float4*)(tn_g + seg*128);
        const float4* e4 = (const float4*)(tn_beta + seg*128);
        #pragma unroll 4
        for (int k4 = 0; k4 < 32; k4 += 2) {
            short8 vv = *(const short8*)&th[row][seg*128 + k4*4];
            float4 g0 = g4[k4], g1 = g4[k4+1];
            float4 e0 = e4[k4], e1 = e4[k4+1];
            float o0 = (bf2f((unsigned short)vv[0]) - mu)*rs*g0.x + e0.x;
            float o1 = (bf2f((unsigned short)vv[1]) - mu)*rs*g0.y + e0.y;
            float o2 = (bf2f((unsigned short)vv[2]) - mu)*rs*g0.z + e0.z;
            float o3 = (bf2f((unsigned short)vv[3]) - mu)*rs*g0.w + e0.w;
            float o4 = (bf2f((unsigned short)vv[4]) - mu)*rs*g1.x + e1.x;
            float o5 = (bf2f((unsigned short)vv[5]) - mu)*rs*g1.y + e1.y;
            float o6 = (bf2f((unsigned short)vv[6]) - mu)*rs*g1.z + e1.z;
            float o7 = (bf2f((unsigned short)vv[7]) - mu)*rs*g1.w + e1.w;
            u32x4 pk;
            pk.x = bfpack(o0, o1);
            pk.y = bfpack(o2, o3);
            pk.z = bfpack(o4, o5);
            pk.w = bfpack(o6, o7);
            *(short8*)&th[row][seg*128 + k4*4] = __builtin_bit_cast(short8, pk);
        }
    }
    __syncthreads();

    // ---- phase B: MFMA (wave wv owns cols [wv*64, wv*64+64)) ----
    int l15 = lane & 15, q = lane >> 4;
    f32x4 acc[4][4];
    #pragma unroll
    for (int rt = 0; rt < 4; ++rt)
        #pragma unroll
        for (int ct = 0; ct < 4; ++ct)
            acc[rt][ct] = (f32x4){0.f, 0.f, 0.f, 0.f};
    const short* tb = tdw_bf + ((size_t)(wv*64 + l15))*MD + q*8;
    #pragma unroll 4
    for (int ks = 0; ks < 16; ++ks) {
        int ko = ks*32 + q*8;
        short8 a0 = *(const short8*)&th[ 0 + l15][ko];
        short8 a1 = *(const short8*)&th[16 + l15][ko];
        short8 a2 = *(const short8*)&th[32 + l15][ko];
        short8 a3 = *(const short8*)&th[48 + l15][ko];
        short8 b0 = *(const short8*)(tb + ks*32);
        short8 b1 = *(const short8*)(tb + 16*MD + ks*32);
        short8 b2 = *(const short8*)(tb + 32*MD + ks*32);
        short8 b3 = *(const short8*)(tb + 48*MD + ks*32);
        acc[0][0] = __builtin_amdgcn_mfma_f32_16x16x32_bf16(a0, b0, acc[0][0], 0,0,0);
        acc[1][0] = __builtin_amdgcn_mfma_f32_16x16x32_bf16(a1, b0, acc[1][0], 0,0,0);
        acc[2][0] = __builtin_amdgcn_mfma_f32_16x16x32_bf16(a2, b0, acc[2][0], 0,0,0);
        acc[3][0] = __builtin_amdgcn_mfma_f32_16x16x32_bf16(a3, b0, acc[3][0], 0,0,0);
        acc[0][1] = __builtin_amdgcn_mfma_f32_16x16x32_bf16(a0, b1, acc[0][1], 0,0,0);
        acc[1][1] = __builtin_amdgcn_mfma_f32_16x16x32_bf16(a1, b1, acc[1][1], 0,0,0);
        acc[2][1] = __builtin_amdgcn_mfma_f32_16x16x32_bf16(a2, b1, acc[2][1], 0,0,0);
        acc[3][1] = __builtin_amdgcn_mfma_f32_16x16x32_bf16(a3, b1, acc[3][1], 0,0,0);
        acc[0][2] = __builtin_amdgcn_mfma_f32_16x16x32_bf16(a0, b2, acc[0][2], 0,0,0);
        acc[1][2] = __builtin_amdgcn_mfma_f32_16x16x32_bf16(a1, b2, acc[1][2], 0,0,0);
        acc[2][2] = __builtin_amdgcn_mfma_f32_16x16x32_bf16(a2, b2, acc[2][2], 0,0,0);
        acc[3][2] = __builtin_amdgcn_mfma_f32_16x16x32_bf16(a3, b2, acc[3][2], 0,0,0);
        acc[0][3] = __builtin_amdgcn_mfma_f32_16x16x32_bf16(a0, b3, acc[0][3], 0,0,0);
        acc[1][3] = __builtin_amdgcn_mfma_f32_16x16x32_bf16(a1, b3, acc[1][3], 0,0,0);
        acc[2][3] = __builtin_amdgcn_mfma_f32_16x16x32_bf16(a2, b3, acc[2][3], 0,0,0);
        acc[3][3] = __builtin_amdgcn_mfma_f32_16x16x32_bf16(a3, b3, acc[3][3], 0,0,0);
    }

    // ---- phase C: bias, stage logits into th (overlay), lse, coalesced Td store ----
    float tbc0 = td_b[wv*64 +  0 + l15];
    float tbc1 = td_b[wv*64 + 16 + l15];
    float tbc2 = td_b[wv*64 + 32 + l15];
    float tbc3 = td_b[wv*64 + 48 + l15];
    #pragma unroll
    for (int rt = 0; rt < 4; ++rt) {
        #pragma unroll
        for (int reg = 0; reg < 4; ++reg) {
            acc[rt][0][reg] += tbc0;
            acc[rt][1][reg] += tbc1;
            acc[rt][2][reg] += tbc2;
            acc[rt][3][reg] += tbc3;
        }
    }
    __syncthreads();   // all waves done reading th fragments
    #pragma unroll
    for (int rt = 0; rt < 4; ++rt) {
        #pragma unroll
        for (int reg = 0; reg < 4; ++reg) {
            int rl = rt*16 + q*4 + reg;
            th[rl][wv*64 +  0 + l15] = (short)f2bf(acc[rt][0][reg]);
            th[rl][wv*64 + 16 + l15] = (short)f2bf(acc[rt][1][reg]);
            th[rl][wv*64 + 32 + l15] = (short)f2bf(acc[rt][2][reg]);
            th[rl][wv*64 + 48 + l15] = (short)f2bf(acc[rt][3][reg]);
        }
    }
    #pragma unroll
    for (int rt = 0; rt < 4; ++rt) {
        #pragma unroll
        for (int reg = 0; reg < 4; ++reg) {
            float m = fmaxf(fmaxf(acc[rt][0][reg], acc[rt][1][reg]),
                            fmaxf(acc[rt][2][reg], acc[rt][3][reg]));
            m = fmaxf(m, __shfl_xor(m, 1));
            m = fmaxf(m, __shfl_xor(m, 2));
            m = fmaxf(m, __shfl_xor(m, 4));
            m = fmaxf(m, __shfl_xor(m, 8));
            if (l15 == 0) pmax[wv][rt*16 + q*4 + reg] = m;
        }
    }
    __syncthreads();
    if (tid < 64)
        gmax[tid] = fmaxf(fmaxf(pmax[0][tid], pmax[1][tid]),
                          fmaxf(pmax[2][tid], pmax[3][tid]));
    __syncthreads();
    #pragma unroll
    for (int rt = 0; rt < 4; ++rt) {
        #pragma unroll
        for (int reg = 0; reg < 4; ++reg) {
            int rw = rt*16 + q*4 + reg;
            float g = gmax[rw];
            float s = __expf(acc[rt][0][reg] - g) + __expf(acc[rt][1][reg] - g)
                    + __expf(acc[rt][2][reg] - g) + __expf(acc[rt][3][reg] - g);
            s += __shfl_xor(s, 1);
            s += __shfl_xor(s, 2);
            s += __shfl_xor(s, 4);
            s += __shfl_xor(s, 8);
            if (l15 == 0) psum[wv][rw] = s;
        }
    }
    __syncthreads();
    if (tid < 64) {
        int r = r0 + tid;
        if (r < NROWS)
            lse_t[r] = gmax[tid] + logf(psum[0][tid] + psum[1][tid] + psum[2][tid] + psum[3][tid]);
    }
    // contiguous 32 KB Td block store: thread -> 128 B
    {
        int srow = tid >> 2, scol = (tid & 3) * 64;
        long gr = (long)r0 + srow;
        if (gr < NROWS) {
            unsigned short* dst = Td + (size_t)gr*Kst + scol;
            #pragma unroll
            for (int k = 0; k < 8; ++k)
                *(short8*)(dst + k*8) = *(const short8*)&th[srow][scol + k*8];
        }
    }
}

// ---------------- K6: gather = 2 table lookups per (t,b), one block per t ----------------
__global__ __launch_bounds__(256) void k_gather2(
    const int* __restrict__ x, const int* __restrict__ z,
    const unsigned short* __restrict__ E, const float* __restrict__ lse_em,
    const unsigned short* __restrict__ Td, const float* __restrict__ lse_t,
    float* __restrict__ out)
{
    int b = threadIdx.x;
    int t = blockIdx.x;
    int zc = z[t*Bb + b];
    int xv = x[t*Bb + b];
    int i0 = (t >= 2) ? z[(t-2)*Bb + b] : Kst;
    int i1 = (t >= 1) ? z[(t-1)*Bb + b] : Kst;
    int lin = i0*KP1 + i1;
    float em = bf2f(E[(size_t)xv*Kst + zc])  - lse_em[zc];
    float tr = bf2f(Td[(size_t)lin*Kst + zc]) - lse_t[lin];
    atomicAdd(&out[b], em + tr);
}

extern "C" void kernel_launch(void* const* d_in, const int* in_sizes, int n_in,
                              void* d_out, int out_size, void* d_ws, size_t ws_size,
                              hipStream_t stream)
{
    const int*   x       = (const int*)  d_in[0];
    const int*   z       = (const int*)  d_in[1];
    const float* lembs   = (const float*)d_in[2];
    const float* tlembs  = (const float*)d_in[3];
    const float* dec_W   = (const float*)d_in[4];
    const float* dec_b   = (const float*)d_in[5];
    const float* em_W    = (const float*)d_in[6];
    const float* em_bias = (const float*)d_in[7];
    const float* em_g    = (const float*)d_in[8];
    const float* em_beta = (const float*)d_in[9];
    const float* td_W    = (const float*)d_in[10];
    const float* td_b    = (const float*)d_in[11];
    const float* tm_W    = (const float*)d_in[12];
    const float* tm_bias = (const float*)d_in[13];
    const float* tn_g    = (const float*)d_in[14];
    const float* tn_beta = (const float*)d_in[15];
    float* out = (float*)d_out;

    float* ws     = (float*)d_ws;
    float* P0     = ws;                    // 131584
    float* P1     = P0 + 131584;           // 131584
    float* lse_em = P1 + 131584;           // 256
    float* part   = lse_em + 256;          // 256*196*2 = 100352
    float* lse_t  = part + 100352;         // 66049 (+pad)
    unsigned short* tdw_bf = (unsigned short*)(lse_t + 66052);  // 131072 ushort
    unsigned short* h_bf   = tdw_bf + 131072;                   // 65536 ushort
    unsigned short* E      = h_bf + 65536;                      // 50176*256 ushort (25.7MB)
    unsigned short* Td     = E + (size_t)50176*256;             // 66049*256 ushort (33.8MB)
    unsigned short* decw_bf = Td;          // OVERLAY: dead before k_trans4 writes Td
    // total ~61.6 MB of workspace

    hipMemsetAsync(out, 0, Bb*sizeof(float), stream);
    k_h<<<Kst, 256, 0, stream>>>(lembs, em_W, em_bias, em_g, em_beta, h_bf);
    k_P<<<KP1, 256, 0, stream>>>(tlembs, tm_W, P0, P1);
    k_tdw<<<128, 256, 0, stream>>>(td_W, tdw_bf);
    k_decw<<<12500, 256, 0, stream>>>(dec_W, decw_bf);
    k_em_mfma2<<<dim3(VB2, 2), 256, 0, stream>>>(decw_bf, dec_b, h_bf, part, E);
    k_em_comb<<<1, Kst, 0, stream>>>(part, lse_em);
    k_trans4<<<(NROWS + 63)/64, 256, 0, stream>>>(tlembs, P0, P1, tm_bias,
                                                  tn_g, tn_beta, (const short*)tdw_bf,
                                                  td_b, lse_t, Td);
    k_gather2<<<Tt, 256, 0, stream>>>(x, z, E, lse_em, Td, lse_t, out);
}

// Round 8
// 364.633 us; speedup vs baseline: 1.1447x; 1.1447x over previous
//
#include <hip/hip_runtime.h>

#define Kst 256
#define Dd 256
#define Vv 50000
#define Tt 512
#define Bb 256
#define KP1 257
#define MD 512
#define NROWS (KP1*KP1)   // 66049
#define EPSf 1e-5f

#define VB2 196           // ceil(50000/256) vocab blocks for MFMA emission kernel

typedef __attribute__((ext_vector_type(8))) short short8;
typedef __attribute__((ext_vector_type(4))) short short4v;
typedef __attribute__((ext_vector_type(4))) float f32x4;
typedef __attribute__((ext_vector_type(4))) unsigned u32x4;
typedef __attribute__((ext_vector_type(2))) unsigned u32x2;

__device__ __forceinline__ unsigned short f2bf(float f) {
    unsigned u = __builtin_bit_cast(unsigned, f);
    unsigned r = (u + 0x7fffu + ((u >> 16) & 1u)) >> 16;
    return (unsigned short)r;
}
__device__ __forceinline__ float bf2f(unsigned short u) {
    return __builtin_bit_cast(float, ((unsigned)u) << 16);
}
__device__ __forceinline__ unsigned bfpack(float lo, float hi) {
    return __builtin_amdgcn_perm(__builtin_bit_cast(unsigned, hi),
                                 __builtin_bit_cast(unsigned, lo), 0x07060302u);
}

// ---------------- K1: emission hidden h = LN(lembs + relu(lembs@em_W.T + b)) -> bf16 ----------------
__global__ __launch_bounds__(256) void k_h(
    const float* __restrict__ lembs, const float* __restrict__ em_W,
    const float* __restrict__ em_bias, const float* __restrict__ em_g,
    const float* __restrict__ em_beta, unsigned short* __restrict__ h_bf)
{
    int k = blockIdx.x, d = threadIdx.x;
    __shared__ float lrow[Dd];
    __shared__ float red[256];
    lrow[d] = lembs[k*Dd + d];
    __syncthreads();
    float acc = em_bias[d];
    const float4* w4 = (const float4*)(em_W + (size_t)d*Dd);
    for (int j4 = 0; j4 < Dd/4; ++j4) {
        float4 w = w4[j4];
        acc += w.x*lrow[4*j4] + w.y*lrow[4*j4+1] + w.z*lrow[4*j4+2] + w.w*lrow[4*j4+3];
    }
    float val = lrow[d] + fmaxf(acc, 0.f);
    red[d] = val; __syncthreads();
    for (int s = 128; s > 0; s >>= 1) { if (d < s) red[d] += red[d+s]; __syncthreads(); }
    float mu = red[0] * (1.f/Dd);
    __syncthreads();
    float c = val - mu;
    red[d] = c*c; __syncthreads();
    for (int s = 128; s > 0; s >>= 1) { if (d < s) red[d] += red[d+s]; __syncthreads(); }
    float rstd = rsqrtf(red[0] * (1.f/Dd) + EPSf);
    float o = c * rstd * em_g[d] + em_beta[d];
    h_bf[k*Dd + d] = f2bf(o);
}

// ---------------- K2: P0[i,j] = tlembs[i]@tm_W[j,0:256], P1[i,j] = tlembs[i]@tm_W[j,256:512] ----------------
__global__ __launch_bounds__(256) void k_P(
    const float* __restrict__ tlembs, const float* __restrict__ tm_W,
    float* __restrict__ P0, float* __restrict__ P1)
{
    int i = blockIdx.x;            // 0..256
    int tid = threadIdx.x;
    __shared__ float tl[Dd];
    tl[tid] = tlembs[i*Dd + tid];
    __syncthreads();
    for (int half = 0; half < 2; ++half) {
        int j = tid + half*256;
        float a0 = 0.f, a1 = 0.f;
        const float4* w4 = (const float4*)(tm_W + (size_t)j*MD);
        for (int l4 = 0; l4 < 64; ++l4) {
            float4 w = w4[l4];
            a0 += w.x*tl[4*l4] + w.y*tl[4*l4+1] + w.z*tl[4*l4+2] + w.w*tl[4*l4+3];
        }
        for (int l4 = 64; l4 < 128; ++l4) {
            float4 w = w4[l4];
            int l = 4*l4 - 256;
            a1 += w.x*tl[l] + w.y*tl[l+1] + w.z*tl[l+2] + w.w*tl[l+3];
        }
        P0[(size_t)i*MD + j] = a0;
        P1[(size_t)i*MD + j] = a1;
    }
}

// ---------------- K2b: td_W -> bf16 copy ----------------
__global__ __launch_bounds__(256) void k_tdw(
    const float* __restrict__ td_W, unsigned short* __restrict__ tdw_bf)
{
    int i = blockIdx.x*256 + threadIdx.x;
    float4 v = ((const float4*)td_W)[i];
    short4v o;
    o.x = (short)f2bf(v.x); o.y = (short)f2bf(v.y);
    o.z = (short)f2bf(v.z); o.w = (short)f2bf(v.w);
    *(short4v*)(tdw_bf + (size_t)i*4) = o;
}

// ---------------- K2c: dec_W -> bf16 copy ----------------
__global__ __launch_bounds__(256) void k_decw(
    const float* __restrict__ dec_W, unsigned short* __restrict__ decw_bf)
{
    int i = blockIdx.x*256 + threadIdx.x;    // grid 12500
    float4 v = ((const float4*)dec_W)[i];
    short4v o;
    o.x = (short)f2bf(v.x); o.y = (short)f2bf(v.y);
    o.z = (short)f2bf(v.z); o.w = (short)f2bf(v.w);
    *(short4v*)(decw_bf + (size_t)i*4) = o;
}

// ---------------- K3 (MFMA): emission logits E[v][k] (bf16) + logsumexp partials ----------------
__global__ __launch_bounds__(256) void k_em_mfma2(
    const unsigned short* __restrict__ decw_bf, const float* __restrict__ dec_b,
    const unsigned short* __restrict__ h_bf, float* __restrict__ part,
    unsigned short* __restrict__ E)
{
    int vb = blockIdx.x, kg = blockIdx.y;
    int tid = threadIdx.x, lane = tid & 63, wv = tid >> 6;
    int l15 = lane & 15, q = lane >> 4;
    __shared__ short hs[128][264];      // 67584 B; reused as st[256][132] for E staging
    __shared__ float red[4][128];
    __shared__ float gmax[128];
    short* st = (short*)hs;

    {
        int row = tid >> 1, c0 = (tid & 1) * 128;
        const short8* src = (const short8*)(h_bf + (size_t)(kg*128 + row)*Dd + c0);
        #pragma unroll
        for (int u = 0; u < 16; ++u)
            *(short8*)&hs[row][c0 + u*8] = src[u];
    }
    __syncthreads();

    const unsigned short* aptr[4];
    #pragma unroll
    for (int mt = 0; mt < 4; ++mt) {
        int v = vb*256 + wv*64 + mt*16 + l15;
        if (v > Vv-1) v = Vv-1;
        aptr[mt] = decw_bf + (size_t)v*Dd + q*8;
    }
    f32x4 acc[4][8];
    #pragma unroll
    for (int mt = 0; mt < 4; ++mt)
        #pragma unroll
        for (int nt = 0; nt < 8; ++nt)
            acc[mt][nt] = (f32x4){0.f,0.f,0.f,0.f};

    for (int ks = 0; ks < 8; ++ks) {
        short8 a[4];
        #pragma unroll
        for (int mt = 0; mt < 4; ++mt)
            a[mt] = *(const short8*)(aptr[mt] + ks*32);
        short8 b[8];
        #pragma unroll
        for (int nt = 0; nt < 8; ++nt)
            b[nt] = *(const short8*)&hs[nt*16 + l15][ks*32 + q*8];
        #pragma unroll
        for (int mt = 0; mt < 4; ++mt)
            #pragma unroll
            for (int nt = 0; nt < 8; ++nt)
                acc[mt][nt] = __builtin_amdgcn_mfma_f32_16x16x32_bf16(a[mt], b[nt], acc[mt][nt], 0,0,0);
    }

    #pragma unroll
    for (int mt = 0; mt < 4; ++mt) {
        int vbase = vb*256 + wv*64 + mt*16 + q*4;
        #pragma unroll
        for (int reg = 0; reg < 4; ++reg) {
            int v = vbase + reg;
            if (v < Vv) {
                float db = dec_b[v];
                #pragma unroll
                for (int nt = 0; nt < 8; ++nt) acc[mt][nt][reg] += db;
            } else {
                #pragma unroll
                for (int nt = 0; nt < 8; ++nt) acc[mt][nt][reg] = -1e30f;
            }
        }
    }
    float mx[8];
    #pragma unroll
    for (int nt = 0; nt < 8; ++nt) {
        float m = -1e30f;
        #pragma unroll
        for (int mt = 0; mt < 4; ++mt)
            #pragma unroll
            for (int reg = 0; reg < 4; ++reg)
                m = fmaxf(m, acc[mt][nt][reg]);
        m = fmaxf(m, __shfl_xor(m, 16));
        m = fmaxf(m, __shfl_xor(m, 32));
        mx[nt] = m;
    }
    if (q == 0)
        #pragma unroll
        for (int nt = 0; nt < 8; ++nt) red[wv][nt*16 + l15] = mx[nt];
    __syncthreads();
    if (tid < 128)
        gmax[tid] = fmaxf(fmaxf(red[0][tid], red[1][tid]), fmaxf(red[2][tid], red[3][tid]));
    #pragma unroll
    for (int mt = 0; mt < 4; ++mt) {
        #pragma unroll
        for (int reg = 0; reg < 4; ++reg) {
            int rl = wv*64 + mt*16 + q*4 + reg;
            #pragma unroll
            for (int nt = 0; nt < 8; ++nt)
                st[rl*132 + nt*16 + l15] = (short)f2bf(acc[mt][nt][reg]);
        }
    }
    __syncthreads();
    float sm[8];
    #pragma unroll
    for (int nt = 0; nt < 8; ++nt) {
        float g = gmax[nt*16 + l15];
        float s = 0.f;
        #pragma unroll
        for (int mt = 0; mt < 4; ++mt)
            #pragma unroll
            for (int reg = 0; reg < 4; ++reg)
                s += __expf(acc[mt][nt][reg] - g);
        s += __shfl_xor(s, 16);
        s += __shfl_xor(s, 32);
        sm[nt] = s;
    }
    if (q == 0)
        #pragma unroll
        for (int nt = 0; nt < 8; ++nt) red[wv][nt*16 + l15] = sm[nt];
    __syncthreads();
    if (tid < 128) {
        int kst = kg*128 + tid;
        float s = red[0][tid] + red[1][tid] + red[2][tid] + red[3][tid];
        part[((size_t)kst*VB2 + vb)*2]     = gmax[tid];
        part[((size_t)kst*VB2 + vb)*2 + 1] = s;
    }
    {
        int rsub = lane >> 4;
        #pragma unroll
        for (int i = 0; i < 16; ++i) {
            int rl = wv*64 + i*4 + rsub;
            int vr = vb*256 + rl;
            if (vr < Vv)
                *(short8*)(E + (size_t)vr*Kst + kg*128 + l15*8) =
                    *(const short8*)&st[rl*132 + l15*8];
        }
    }
}

// ---------------- K4: combine partials -> lse_em[k]; 256 blocks x 64 lanes ----------------
__global__ __launch_bounds__(64) void k_em_comb2(
    const float* __restrict__ part, float* __restrict__ lse_em)
{
    int k = blockIdx.x, lane = threadIdx.x;
    float m = -1e30f, s = 0.f;
    for (int vb = lane; vb < VB2; vb += 64) {
        float m2 = part[((size_t)k*VB2+vb)*2], s2 = part[((size_t)k*VB2+vb)*2+1];
        if (m2 > m) { s = s*__expf(m - m2) + s2; m = m2; }
        else          s += s2*__expf(m2 - m);
    }
    #pragma unroll
    for (int d = 1; d < 64; d <<= 1) {
        float mo = __shfl_xor(m, d), so = __shfl_xor(s, d);
        float mn = fmaxf(m, mo);
        s = s*__expf(m - mn) + so*__expf(mo - mn);
        m = mn;
    }
    if (lane == 0) lse_em[k] = m + logf(s);
}

// ---------------- K5 (MFMA): transition logits, 32-row tiles -> 4 blocks/CU ----------------
__global__ __launch_bounds__(256) void k_trans5(
    const float* __restrict__ tlembs, const float* __restrict__ P0,
    const float* __restrict__ P1, const float* __restrict__ tm_bias,
    const float* __restrict__ tn_g, const float* __restrict__ tn_beta,
    const short* __restrict__ tdw_bf, const float* __restrict__ td_b,
    float* __restrict__ lse_t, unsigned short* __restrict__ Td)
{
    __shared__ short th[32][520];          // 33.3 KB
    __shared__ float rstat[32][18];        // s at [seg], ss at [9+seg]
    __shared__ float musig[32][2];
    __shared__ float pmax[4][32], psum[4][32], gmax[32];
    int tid = threadIdx.x, lane = tid & 63, wv = tid >> 6;
    int r0 = blockIdx.x * 32;

    // ---- phase A pass 1: coalesced, dependency-free staging (wave-per-row, 8 rows/wave) ----
    {
        const float4* bias0 = (const float4*)tm_bias;
        const float4* bias1 = (const float4*)(tm_bias + 256);
        for (int i = 0; i < 8; ++i) {
            int row = wv*8 + i;
            int r = r0 + row; if (r >= NROWS) r = NROWS - 1;
            int i0 = r / KP1, i1 = r - i0*KP1;
            float4 a0 = ((const float4*)(P0 + (size_t)i0*MD))[lane];
            float4 b0 = ((const float4*)(P1 + (size_t)i1*MD))[lane];
            float4 t0 = ((const float4*)(tlembs + (size_t)i0*Dd))[lane];
            float4 c0 = bias0[lane];
            float4 a1 = ((const float4*)(P0 + (size_t)i0*MD + 256))[lane];
            float4 b1 = ((const float4*)(P1 + (size_t)i1*MD + 256))[lane];
            float4 t1 = ((const float4*)(tlembs + (size_t)i1*Dd))[lane];
            float4 c1 = bias1[lane];
            float v0 = t0.x + fmaxf(a0.x+b0.x+c0.x, 0.f);
            float v1 = t0.y + fmaxf(a0.y+b0.y+c0.y, 0.f);
            float v2 = t0.z + fmaxf(a0.z+b0.z+c0.z, 0.f);
            float v3 = t0.w + fmaxf(a0.w+b0.w+c0.w, 0.f);
            float v4 = t1.x + fmaxf(a1.x+b1.x+c1.x, 0.f);
            float v5 = t1.y + fmaxf(a1.y+b1.y+c1.y, 0.f);
            float v6 = t1.z + fmaxf(a1.z+b1.z+c1.z, 0.f);
            float v7 = t1.w + fmaxf(a1.w+b1.w+c1.w, 0.f);
            u32x2 p0; p0.x = bfpack(v0, v1); p0.y = bfpack(v2, v3);
            u32x2 p1; p1.x = bfpack(v4, v5); p1.y = bfpack(v6, v7);
            *(u32x2*)&th[row][lane*4]       = p0;
            *(u32x2*)&th[row][256 + lane*4] = p1;
        }
    }
    __syncthreads();
    // ---- pass 2: LN stats from LDS (thread = (row, 64-col segment)) ----
    {
        int row = tid & 31, seg = tid >> 5;      // 8 segs x 64 cols
        float s = 0.f, ss = 0.f;
        #pragma unroll
        for (int k8 = 0; k8 < 8; ++k8) {
            short8 vv = *(const short8*)&th[row][seg*64 + k8*8];
            #pragma unroll
            for (int e = 0; e < 8; ++e) {
                float f = bf2f((unsigned short)vv[e]);
                s += f; ss += f*f;
            }
        }
        rstat[row][seg]     = s;
        rstat[row][9 + seg] = ss;
    }
    __syncthreads();
    if (tid < 32) {
        float s  = ((rstat[tid][0] + rstat[tid][1]) + (rstat[tid][2] + rstat[tid][3]))
                 + ((rstat[tid][4] + rstat[tid][5]) + (rstat[tid][6] + rstat[tid][7]));
        float ss = ((rstat[tid][9] + rstat[tid][10]) + (rstat[tid][11] + rstat[tid][12]))
                 + ((rstat[tid][13] + rstat[tid][14]) + (rstat[tid][15] + rstat[tid][16]));
        float mu = s * (1.f/MD);
        musig[tid][0] = mu;
        musig[tid][1] = rsqrtf(ss*(1.f/MD) - mu*mu + EPSf);
    }
    __syncthreads();
    // ---- pass 3: normalize in place (thread = (row, 64-col segment)) ----
    {
        int row = tid & 31, seg = tid >> 5;
        float mu = musig[row][0], rs = musig[row][1];
        const float4* g4 = (const float4*)(tn_g + seg*64);
        const float4* e4 = (const float4*)(tn_beta + seg*64);
        #pragma unroll
        for (int k4 = 0; k4 < 16; k4 += 2) {
            short8 vv = *(const short8*)&th[row][seg*64 + k4*4];
            float4 g0 = g4[k4], g1 = g4[k4+1];
            float4 e0 = e4[k4], e1 = e4[k4+1];
            float o0 = (bf2f((unsigned short)vv[0]) - mu)*rs*g0.x + e0.x;
            float o1 = (bf2f((unsigned short)vv[1]) - mu)*rs*g0.y + e0.y;
            float o2 = (bf2f((unsigned short)vv[2]) - mu)*rs*g0.z + e0.z;
            float o3 = (bf2f((unsigned short)vv[3]) - mu)*rs*g0.w + e0.w;
            float o4 = (bf2f((unsigned short)vv[4]) - mu)*rs*g1.x + e1.x;
            float o5 = (bf2f((unsigned short)vv[5]) - mu)*rs*g1.y + e1.y;
            float o6 = (bf2f((unsigned short)vv[6]) - mu)*rs*g1.z + e1.z;
            float o7 = (bf2f((unsigned short)vv[7]) - mu)*rs*g1.w + e1.w;
            u32x4 pk;
            pk.x = bfpack(o0, o1);
            pk.y = bfpack(o2, o3);
            pk.z = bfpack(o4, o5);
            pk.w = bfpack(o6, o7);
            *(short8*)&th[row][seg*64 + k4*4] = __builtin_bit_cast(short8, pk);
        }
    }
    __syncthreads();

    // ---- phase B: MFMA (wave wv owns cols [wv*64, wv*64+64), 2 row-tiles) ----
    int l15 = lane & 15, q = lane >> 4;
    f32x4 acc[2][4];
    #pragma unroll
    for (int rt = 0; rt < 2; ++rt)
        #pragma unroll
        for (int ct = 0; ct < 4; ++ct)
            acc[rt][ct] = (f32x4){0.f, 0.f, 0.f, 0.f};
    const short* tb = tdw_bf + ((size_t)(wv*64 + l15))*MD + q*8;
    #pragma unroll 4
    for (int ks = 0; ks < 16; ++ks) {
        int ko = ks*32 + q*8;
        short8 a0 = *(const short8*)&th[ 0 + l15][ko];
        short8 a1 = *(const short8*)&th[16 + l15][ko];
        short8 b0 = *(const short8*)(tb + ks*32);
        short8 b1 = *(const short8*)(tb + 16*MD + ks*32);
        short8 b2 = *(const short8*)(tb + 32*MD + ks*32);
        short8 b3 = *(const short8*)(tb + 48*MD + ks*32);
        acc[0][0] = __builtin_amdgcn_mfma_f32_16x16x32_bf16(a0, b0, acc[0][0], 0,0,0);
        acc[1][0] = __builtin_amdgcn_mfma_f32_16x16x32_bf16(a1, b0, acc[1][0], 0,0,0);
        acc[0][1] = __builtin_amdgcn_mfma_f32_16x16x32_bf16(a0, b1, acc[0][1], 0,0,0);
        acc[1][1] = __builtin_amdgcn_mfma_f32_16x16x32_bf16(a1, b1, acc[1][1], 0,0,0);
        acc[0][2] = __builtin_amdgcn_mfma_f32_16x16x32_bf16(a0, b2, acc[0][2], 0,0,0);
        acc[1][2] = __builtin_amdgcn_mfma_f32_16x16x32_bf16(a1, b2, acc[1][2], 0,0,0);
        acc[0][3] = __builtin_amdgcn_mfma_f32_16x16x32_bf16(a0, b3, acc[0][3], 0,0,0);
        acc[1][3] = __builtin_amdgcn_mfma_f32_16x16x32_bf16(a1, b3, acc[1][3], 0,0,0);
    }

    // ---- phase C: bias, lse, stage logits via th overlay, coalesced Td store ----
    float tbc0 = td_b[wv*64 +  0 + l15];
    float tbc1 = td_b[wv*64 + 16 + l15];
    float tbc2 = td_b[wv*64 + 32 + l15];
    float tbc3 = td_b[wv*64 + 48 + l15];
    #pragma unroll
    for (int rt = 0; rt < 2; ++rt) {
        #pragma unroll
        for (int reg = 0; reg < 4; ++reg) {
            acc[rt][0][reg] += tbc0;
            acc[rt][1][reg] += tbc1;
            acc[rt][2][reg] += tbc2;
            acc[rt][3][reg] += tbc3;
        }
    }
    __syncthreads();   // all waves done reading th fragments
    #pragma unroll
    for (int rt = 0; rt < 2; ++rt) {
        #pragma unroll
        for (int reg = 0; reg < 4; ++reg) {
            int rl = rt*16 + q*4 + reg;
            th[rl][wv*64 +  0 + l15] = (short)f2bf(acc[rt][0][reg]);
            th[rl][wv*64 + 16 + l15] = (short)f2bf(acc[rt][1][reg]);
            th[rl][wv*64 + 32 + l15] = (short)f2bf(acc[rt][2][reg]);
            th[rl][wv*64 + 48 + l15] = (short)f2bf(acc[rt][3][reg]);
        }
    }
    #pragma unroll
    for (int rt = 0; rt < 2; ++rt) {
        #pragma unroll
        for (int reg = 0; reg < 4; ++reg) {
            float m = fmaxf(fmaxf(acc[rt][0][reg], acc[rt][1][reg]),
                            fmaxf(acc[rt][2][reg], acc[rt][3][reg]));
            m = fmaxf(m, __shfl_xor(m, 1));
            m = fmaxf(m, __shfl_xor(m, 2));
            m = fmaxf(m, __shfl_xor(m, 4));
            m = fmaxf(m, __shfl_xor(m, 8));
            if (l15 == 0) pmax[wv][rt*16 + q*4 + reg] = m;
        }
    }
    __syncthreads();
    if (tid < 32)
        gmax[tid] = fmaxf(fmaxf(pmax[0][tid], pmax[1][tid]),
                          fmaxf(pmax[2][tid], pmax[3][tid]));
    __syncthreads();
    #pragma unroll
    for (int rt = 0; rt < 2; ++rt) {
        #pragma unroll
        for (int reg = 0; reg < 4; ++reg) {
            int rw = rt*16 + q*4 + reg;
            float g = gmax[rw];
            float s = __expf(acc[rt][0][reg] - g) + __expf(acc[rt][1][reg] - g)
                    + __expf(acc[rt][2][reg] - g) + __expf(acc[rt][3][reg] - g);
            s += __shfl_xor(s, 1);
            s += __shfl_xor(s, 2);
            s += __shfl_xor(s, 4);
            s += __shfl_xor(s, 8);
            if (l15 == 0) psum[wv][rw] = s;
        }
    }
    __syncthreads();
    if (tid < 32) {
        int r = r0 + tid;
        if (r < NROWS)
            lse_t[r] = gmax[tid] + logf(psum[0][tid] + psum[1][tid] + psum[2][tid] + psum[3][tid]);
    }
    // contiguous 16 KB Td block store: thread -> 64 B (row = tid>>3, chunk = (tid&7)*32)
    {
        int srow = tid >> 3, scol = (tid & 7) * 32;
        long gr = (long)r0 + srow;
        if (gr < NROWS) {
            unsigned short* dst = Td + (size_t)gr*Kst + scol;
            #pragma unroll
            for (int k = 0; k < 4; ++k)
                *(short8*)(dst + k*8) = *(const short8*)&th[srow][scol + k*8];
        }
    }
}

// ---------------- K6: gather = 2 table lookups per (t,b), one block per t ----------------
__global__ __launch_bounds__(256) void k_gather2(
    const int* __restrict__ x, const int* __restrict__ z,
    const unsigned short* __restrict__ E, const float* __restrict__ lse_em,
    const unsigned short* __restrict__ Td, const float* __restrict__ lse_t,
    float* __restrict__ out)
{
    int b = threadIdx.x;
    int t = blockIdx.x;
    int zc = z[t*Bb + b];
    int xv = x[t*Bb + b];
    int i0 = (t >= 2) ? z[(t-2)*Bb + b] : Kst;
    int i1 = (t >= 1) ? z[(t-1)*Bb + b] : Kst;
    int lin = i0*KP1 + i1;
    float em = bf2f(E[(size_t)xv*Kst + zc])  - lse_em[zc];
    float tr = bf2f(Td[(size_t)lin*Kst + zc]) - lse_t[lin];
    atomicAdd(&out[b], em + tr);
}

extern "C" void kernel_launch(void* const* d_in, const int* in_sizes, int n_in,
                              void* d_out, int out_size, void* d_ws, size_t ws_size,
                              hipStream_t stream)
{
    const int*   x       = (const int*)  d_in[0];
    const int*   z       = (const int*)  d_in[1];
    const float* lembs   = (const float*)d_in[2];
    const float* tlembs  = (const float*)d_in[3];
    const float* dec_W   = (const float*)d_in[4];
    const float* dec_b   = (const float*)d_in[5];
    const float* em_W    = (const float*)d_in[6];
    const float* em_bias = (const float*)d_in[7];
    const float* em_g    = (const float*)d_in[8];
    const float* em_beta = (const float*)d_in[9];
    const float* td_W    = (const float*)d_in[10];
    const float* td_b    = (const float*)d_in[11];
    const float* tm_W    = (const float*)d_in[12];
    const float* tm_bias = (const float*)d_in[13];
    const float* tn_g    = (const float*)d_in[14];
    const float* tn_beta = (const float*)d_in[15];
    float* out = (float*)d_out;

    float* ws     = (float*)d_ws;
    float* P0     = ws;                    // 131584
    float* P1     = P0 + 131584;           // 131584
    float* lse_em = P1 + 131584;           // 256
    float* part   = lse_em + 256;          // 256*196*2 = 100352
    float* lse_t  = part + 100352;         // 66049 (+pad)
    unsigned short* tdw_bf = (unsigned short*)(lse_t + 66052);  // 131072 ushort
    unsigned short* h_bf   = tdw_bf + 131072;                   // 65536 ushort
    unsigned short* E      = h_bf + 65536;                      // 50176*256 ushort (25.7MB)
    unsigned short* Td     = E + (size_t)50176*256;             // 66049*256 ushort (33.8MB)
    unsigned short* decw_bf = Td;          // OVERLAY: dead before k_trans5 writes Td

    hipMemsetAsync(out, 0, Bb*sizeof(float), stream);
    k_h<<<Kst, 256, 0, stream>>>(lembs, em_W, em_bias, em_g, em_beta, h_bf);
    k_P<<<KP1, 256, 0, stream>>>(tlembs, tm_W, P0, P1);
    k_tdw<<<128, 256, 0, stream>>>(td_W, tdw_bf);
    k_decw<<<12500, 256, 0, stream>>>(dec_W, decw_bf);
    k_em_mfma2<<<dim3(VB2, 2), 256, 0, stream>>>(decw_bf, dec_b, h_bf, part, E);
    k_em_comb2<<<Kst, 64, 0, stream>>>(part, lse_em);
    k_trans5<<<(NROWS + 31)/32, 256, 0, stream>>>(tlembs, P0, P1, tm_bias,
                                                  tn_g, tn_beta, (const short*)tdw_bf,
                                                  td_b, lse_t, Td);
    k_gather2<<<Tt, 256, 0, stream>>>(x, z, E, lse_em, Td, lse_t, out);
}